// Round 10
// baseline (1258.603 us; speedup 1.0000x reference)
//
#include <hip/hip_runtime.h>

// GraphProjection: out[N,963] = concat(verts[N,3], proj(f0)[N,64], proj(f1)[N,128],
//                                      proj(f2)[N,256], proj(f3)[N,512])
// Degenerate "bilinear": weights collapse to w11 = (x2-x1)*(y2-y1) in {0,1}.
//
// V10: locality-sorted wave-per-row.
// Theory: gp is fabric-volume-bound (192.6 MB writes + 192.6 MB reads =
// 4.8 TB/s at 80us). Reads miss L2 because the 24 MB/XCD write sweep evicts
// the 1.5 MB tables between reuses (random vertex order = whole-kernel reuse
// distance). Fix: counting-sort rows by level-3 cell (50 buckets) so
// consecutive waves share table slices (~30 KB working set, wave-adjacent
// reuse) -> reads become L1/L2 hits; fabric traffic ~halves.
//  - output identical under any processing order (row n always gets row n's
//    data), so atomic-order nondeterminism in the permutation is safe.
//  - x4 grid anchored at col 3 (boundaries ==3 mod 4): all loads aligned
//    dwordx4; plain stores (NT measured -25us in V4).

static constexpr int NV      = 50000;
static constexpr int TOTAL   = 963 * NV;          // 48,150,000

// transposed feature sizes (floats): [S*S, C]
static constexpr int T0 = 56 * 56 * 64;   // 200,704
static constexpr int T1 = 28 * 28 * 128;  // 100,352
static constexpr int T2 = 14 * 14 * 256;  // 50,176
static constexpr int T3 = 7 * 7 * 512;    // 25,088
static constexpr int TSUM = T0 + T1 + T2 + T3; // 376,320
static constexpr int ZN   = 516;          // zero block (>=512 needed)
static constexpr int NB   = 50;           // 49 level-3 cells + 1 invalid

typedef float f32x4 __attribute__((ext_vector_type(4)));

__device__ __forceinline__ void store4_u(float* p, f32x4 v) {
  __builtin_memcpy(p, &v, 16);
}

__device__ __forceinline__ void proj_hw(const float* __restrict__ verts, int n,
                                        float& h, float& w) {
  float v0 = verts[3 * n + 0];
  float v1 = verts[3 * n + 1];
  float v2 = verts[3 * n + 2];
  // match numpy fp32 exactly: no FMA contraction, IEEE rn division
  h = __fadd_rn(__fmul_rn(248.0f, __fdiv_rn(v1, v2)), 111.5f);
  w = __fadd_rn(__fmul_rn(248.0f, __fdiv_rn(v0, -v2)), 111.5f);
  h = fminf(fmaxf(h, 0.0f), 223.0f);
  w = fminf(fmaxf(w, 0.0f), 223.0f);
}

__device__ __forceinline__ int level_off(float h, float w, float scale, int S) {
  float x = h * scale;  // scale = S/224 is an exact power of two
  float y = w * scale;
  int x1 = (int)floorf(x);
  int x2 = min((int)ceilf(x), S - 1);
  int y1 = (int)floorf(y);
  int y2 = min((int)ceilf(y), S - 1);
  return (x2 > x1 && y2 > y1) ? (x1 * S + y1) : -1;
}

// [C,S,S] -> [S*S, C]; zero-fills the ZN-float zero block; zeroes the
// NB-entry bucket histogram (runs first on the stream).
__global__ __launch_bounds__(256) void transpose_k(
    const float* __restrict__ f0, const float* __restrict__ f1,
    const float* __restrict__ f2, const float* __restrict__ f3,
    float* __restrict__ t0, float* __restrict__ t1,
    float* __restrict__ t2, float* __restrict__ t3,
    float* __restrict__ zeros, int* __restrict__ hist) {
  int i = blockIdx.x * 256 + threadIdx.x;
  if (i < T0) { int off = i >> 6, c = i & 63;  t0[i] = f0[c * 3136 + off]; return; }
  i -= T0;
  if (i < T1) { int off = i >> 7, c = i & 127; t1[i] = f1[c * 784 + off];  return; }
  i -= T1;
  if (i < T2) { int off = i >> 8, c = i & 255; t2[i] = f2[c * 196 + off];  return; }
  i -= T2;
  if (i < T3) { int off = i >> 9, c = i & 511; t3[i] = f3[c * 49 + off];   return; }
  i -= T3;
  if (i < ZN) { zeros[i] = 0.0f; return; }
  i -= ZN;
  if (i < NB) hist[i] = 0;
}

__global__ __launch_bounds__(256) void prep_params_k(const float* __restrict__ verts,
                                                     int* __restrict__ params,
                                                     int* __restrict__ hist) {
  int n = blockIdx.x * 256 + threadIdx.x;
  if (n >= NV) return;
  float h, w;
  proj_hw(verts, n, h, w);
  int p0 = level_off(h, w, 0.25f,    56);
  int p1 = level_off(h, w, 0.125f,   28);
  int p2 = level_off(h, w, 0.0625f,  14);
  int p3 = level_off(h, w, 0.03125f, 7);
  params[4 * n + 0] = p0;
  params[4 * n + 1] = p1;
  params[4 * n + 2] = p2;
  params[4 * n + 3] = p3;
  atomicAdd(&hist[(p3 < 0) ? 49 : p3], 1);
}

__global__ void scan_k(const int* __restrict__ hist, int* __restrict__ bases) {
  if (threadIdx.x == 0) {
    int acc = 0;
    for (int i = 0; i < NB; ++i) { bases[i] = acc; acc += hist[i]; }
  }
}

__global__ __launch_bounds__(256) void scatter_k(const int* __restrict__ params,
                                                 int* __restrict__ bases,
                                                 int* __restrict__ order) {
  int n = blockIdx.x * 256 + threadIdx.x;
  if (n >= NV) return;
  int p3 = params[4 * n + 3];
  int pos = atomicAdd(&bases[(p3 < 0) ? 49 : p3], 1);
  order[pos] = n;
}

// Wave-per-row in bucket-sorted order: 64 lanes copy row order[wid].
// Cols [0,3)=verts, [3,67)=t0, [67,195)=t1, [195,451)=t2, [451,963)=t3.
__global__ __launch_bounds__(256) void gp_sorted_k(
    const float* __restrict__ verts,
    const float* __restrict__ t0, const float* __restrict__ t1,
    const float* __restrict__ t2, const float* __restrict__ t3,
    const float* __restrict__ zeros,
    const int* __restrict__ params,
    const int* __restrict__ order,
    float* __restrict__ out) {
  int wid  = (blockIdx.x * 256 + threadIdx.x) >> 6;
  int lane = threadIdx.x & 63;
  if (wid >= NV) return;
  const int ws = __builtin_amdgcn_readfirstlane(wid);
  const int n  = __builtin_amdgcn_readfirstlane(order[ws]);  // wave-uniform

  // head elements (vector load, issued early)
  float hv = 0.0f;
  if (lane < 3) hv = verts[3 * n + lane];

  // wave-uniform param fetch (scalar path)
  int4 pv = *reinterpret_cast<const int4*>(params + 4 * n);
  int p0 = __builtin_amdgcn_readfirstlane(pv.x);
  int p1 = __builtin_amdgcn_readfirstlane(pv.y);
  int p2 = __builtin_amdgcn_readfirstlane(pv.z);
  int p3 = __builtin_amdgcn_readfirstlane(pv.w);

  // p<0 redirects into the zero block; offsets keep 16B alignment on the
  // x4 grid since (col - start_r) == 0 (mod 4).
  const float* s0 = ((p0 >= 0) ? t0 + (p0 << 6) : zeros) - 3;
  const float* s1 = ((p1 >= 0) ? t1 + (p1 << 7) : zeros) - 67;
  const float* s2 = ((p2 >= 0) ? t2 + (p2 << 8) : zeros) - 195;
  const float* s3 = ((p3 >= 0) ? t3 + (p3 << 9) : zeros) - 451;

  float* o = out + 963 * n;

  int col0 = 3 + 4 * lane;            // [3,259): t0|t1|t2
  int col1 = 259 + 4 * lane;          // [259,515): t2|t3
  int col2 = 515 + 4 * lane;          // [515,771): t3
  int col3 = 771 + 4 * lane;          // [771,963) lane<48: t3
  const float* b0 = (lane < 16) ? s0 : (lane < 48) ? s1 : s2;
  const float* b1 = (lane < 48) ? s2 : s3;
  f32x4 a = *reinterpret_cast<const f32x4*>(b0 + col0);
  f32x4 b = *reinterpret_cast<const f32x4*>(b1 + col1);
  f32x4 c = *reinterpret_cast<const f32x4*>(s3 + col2);
  f32x4 d;
  if (lane < 48) d = *reinterpret_cast<const f32x4*>(s3 + col3);

  if (lane < 3) o[lane] = hv;
  store4_u(o + col0, a);
  store4_u(o + col1, b);
  store4_u(o + col2, c);
  if (lane < 48) store4_u(o + col3, d);
}

// ---------- fallback paths ----------
template <int MODE>
__device__ __forceinline__ int get_off(const int* __restrict__ params,
                                       const float* __restrict__ verts,
                                       int n, int k, float scale, int S) {
  if (MODE < 2) return params[4 * n + k];
  float h, w;
  proj_hw(verts, n, h, w);
  return level_off(h, w, scale, S);
}

__global__ __launch_bounds__(256) void prep_only_k(const float* __restrict__ verts,
                                                   int* __restrict__ params) {
  int n = blockIdx.x * 256 + threadIdx.x;
  if (n >= NV) return;
  float h, w;
  proj_hw(verts, n, h, w);
  params[4 * n + 0] = level_off(h, w, 0.25f,    56);
  params[4 * n + 1] = level_off(h, w, 0.125f,   28);
  params[4 * n + 2] = level_off(h, w, 0.0625f,  14);
  params[4 * n + 3] = level_off(h, w, 0.03125f, 7);
}

static constexpr int B_VERTS = 3 * NV;            // 150,000
static constexpr int B_F0    = B_VERTS + 64 * NV; // 3,350,000
static constexpr int B_F1    = B_F0 + 128 * NV;   // 9,750,000
static constexpr int B_F2    = B_F1 + 256 * NV;   // 22,550,000

template <int MODE>
__global__ __launch_bounds__(256) void gp_main_k(
    const float* __restrict__ verts,
    const float* __restrict__ f0, const float* __restrict__ f1,
    const float* __restrict__ f2, const float* __restrict__ f3,
    const int* __restrict__ params, float* __restrict__ out) {
  int j = blockIdx.x * 256 + threadIdx.x;
  if (j >= TOTAL) return;

  if (j < B_VERTS) {
    int n = j / 3;
    int col = j - 3 * n;
    out[n * 963 + col] = verts[j];
    return;
  }

  int n, outcol;
  float val = 0.0f;
  if (j < B_F0) {
    int t = j - B_VERTS; n = t >> 6; int c = t & 63;
    int off = get_off<MODE>(params, verts, n, 0, 0.25f, 56);
    if (off >= 0) val = f0[c * 3136 + off];
    outcol = 3 + c;
  } else if (j < B_F1) {
    int t = j - B_F0; n = t >> 7; int c = t & 127;
    int off = get_off<MODE>(params, verts, n, 1, 0.125f, 28);
    if (off >= 0) val = f1[c * 784 + off];
    outcol = 67 + c;
  } else if (j < B_F2) {
    int t = j - B_F1; n = t >> 8; int c = t & 255;
    int off = get_off<MODE>(params, verts, n, 2, 0.0625f, 14);
    if (off >= 0) val = f2[c * 196 + off];
    outcol = 195 + c;
  } else {
    int t = j - B_F2; n = t >> 9; int c = t & 511;
    int off = get_off<MODE>(params, verts, n, 3, 0.03125f, 7);
    if (off >= 0) val = f3[c * 49 + off];
    outcol = 451 + c;
  }
  out[n * 963 + outcol] = val;
}

extern "C" void kernel_launch(void* const* d_in, const int* in_sizes, int n_in,
                              void* d_out, int out_size, void* d_ws, size_t ws_size,
                              hipStream_t stream) {
  const float* f0    = (const float*)d_in[0];
  const float* f1    = (const float*)d_in[1];
  const float* f2    = (const float*)d_in[2];
  const float* f3    = (const float*)d_in[3];
  const float* verts = (const float*)d_in[4];
  float* out = (float*)d_out;

  const size_t PARAM_BYTES = (size_t)NV * 4 * sizeof(int);            // 800,000
  const size_t TAB_BYTES   = (size_t)(TSUM + ZN) * sizeof(float);     // 1,507,344
  const size_t SORT_BYTES  = PARAM_BYTES + TAB_BYTES
                           + (size_t)(2 * NB) * sizeof(int)           // hist+bases
                           + (size_t)NV * sizeof(int);                // order
  const size_t FULL_BYTES  = PARAM_BYTES + TAB_BYTES;

  if (ws_size >= SORT_BYTES) {
    int*   params = (int*)d_ws;
    float* t0 = (float*)((char*)d_ws + PARAM_BYTES);
    float* t1 = t0 + T0;
    float* t2 = t1 + T1;
    float* t3 = t2 + T2;
    float* zeros = t3 + T3;
    int*   hist  = (int*)(zeros + ZN);
    int*   bases = hist + NB;
    int*   order = bases + NB;
    transpose_k<<<(TSUM + ZN + NB + 255) / 256, 256, 0, stream>>>(
        f0, f1, f2, f3, t0, t1, t2, t3, zeros, hist);
    prep_params_k<<<(NV + 255) / 256, 256, 0, stream>>>(verts, params, hist);
    scan_k<<<1, 64, 0, stream>>>(hist, bases);
    scatter_k<<<(NV + 255) / 256, 256, 0, stream>>>(params, bases, order);
    const int rowBlocks = (NV * 64 + 255) / 256;  // 12,500
    gp_sorted_k<<<rowBlocks, 256, 0, stream>>>(verts, t0, t1, t2, t3, zeros,
                                               params, order, out);
  } else if (ws_size >= PARAM_BYTES) {
    int* params = (int*)d_ws;
    prep_only_k<<<(NV + 255) / 256, 256, 0, stream>>>(verts, params);
    gp_main_k<1><<<(TOTAL + 255) / 256, 256, 0, stream>>>(verts, f0, f1, f2, f3, params, out);
  } else {
    gp_main_k<2><<<(TOTAL + 255) / 256, 256, 0, stream>>>(verts, f0, f1, f2, f3, nullptr, out);
  }
}

// Round 11
// 219.618 us; speedup vs baseline: 5.7309x; 5.7309x over previous
//
#include <hip/hip_runtime.h>

// GraphProjection: out[N,963] = concat(verts[N,3], proj(f0)[N,64], proj(f1)[N,128],
//                                      proj(f2)[N,256], proj(f3)[N,512])
// Degenerate "bilinear": weights collapse to w11 = (x2-x1)*(y2-y1) in {0,1}.
//
// V11: locality-sorted wave-per-row, CONTENTION-FREE counting sort.
// V10's theory stands (gp is fabric-read-bound: the 24 MB/XCD write sweep
// evicts the 1.5 MB tables between reuses at random vertex order), but V10's
// probe was destroyed by 50k device-scope atomics on 50 addresses (2x 528us).
// V11 sorts with block-local LDS histograms + a tiny deterministic scan:
//   block_hist_k (LDS atomics) -> scan_k (1 block) -> scatter_k (LDS atomics
//   seeded from blockoff) -> order[]. ~10us total, no global contention.
// gp_sorted_k is byte-identical to V10 -> this run isolates the locality lever.

static constexpr int NV      = 50000;
static constexpr int TOTAL   = 963 * NV;          // 48,150,000

// transposed feature sizes (floats): [S*S, C]
static constexpr int T0 = 56 * 56 * 64;   // 200,704
static constexpr int T1 = 28 * 28 * 128;  // 100,352
static constexpr int T2 = 14 * 14 * 256;  // 50,176
static constexpr int T3 = 7 * 7 * 512;    // 25,088
static constexpr int TSUM = T0 + T1 + T2 + T3; // 376,320
static constexpr int ZN   = 516;          // zero block (>=512 needed)
static constexpr int NB   = 50;           // 49 level-3 cells + 1 invalid
static constexpr int NBLK = (NV + 255) / 256;  // 196 sort blocks

typedef float f32x4 __attribute__((ext_vector_type(4)));

__device__ __forceinline__ void store4_u(float* p, f32x4 v) {
  __builtin_memcpy(p, &v, 16);
}

__device__ __forceinline__ void proj_hw(const float* __restrict__ verts, int n,
                                        float& h, float& w) {
  float v0 = verts[3 * n + 0];
  float v1 = verts[3 * n + 1];
  float v2 = verts[3 * n + 2];
  // match numpy fp32 exactly: no FMA contraction, IEEE rn division
  h = __fadd_rn(__fmul_rn(248.0f, __fdiv_rn(v1, v2)), 111.5f);
  w = __fadd_rn(__fmul_rn(248.0f, __fdiv_rn(v0, -v2)), 111.5f);
  h = fminf(fmaxf(h, 0.0f), 223.0f);
  w = fminf(fmaxf(w, 0.0f), 223.0f);
}

__device__ __forceinline__ int level_off(float h, float w, float scale, int S) {
  float x = h * scale;  // scale = S/224 is an exact power of two
  float y = w * scale;
  int x1 = (int)floorf(x);
  int x2 = min((int)ceilf(x), S - 1);
  int y1 = (int)floorf(y);
  int y2 = min((int)ceilf(y), S - 1);
  return (x2 > x1 && y2 > y1) ? (x1 * S + y1) : -1;
}

// [C,S,S] -> [S*S, C]; zero-fills the ZN-float zero block.
__global__ __launch_bounds__(256) void transpose_k(
    const float* __restrict__ f0, const float* __restrict__ f1,
    const float* __restrict__ f2, const float* __restrict__ f3,
    float* __restrict__ t0, float* __restrict__ t1,
    float* __restrict__ t2, float* __restrict__ t3,
    float* __restrict__ zeros) {
  int i = blockIdx.x * 256 + threadIdx.x;
  if (i < T0) { int off = i >> 6, c = i & 63;  t0[i] = f0[c * 3136 + off]; return; }
  i -= T0;
  if (i < T1) { int off = i >> 7, c = i & 127; t1[i] = f1[c * 784 + off];  return; }
  i -= T1;
  if (i < T2) { int off = i >> 8, c = i & 255; t2[i] = f2[c * 196 + off];  return; }
  i -= T2;
  if (i < T3) { int off = i >> 9, c = i & 511; t3[i] = f3[c * 49 + off];   return; }
  i -= T3;
  if (i < ZN) zeros[i] = 0.0f;
}

// params only — no atomics (V10's prep atomics cost ~528us).
__global__ __launch_bounds__(256) void prep_params_k(const float* __restrict__ verts,
                                                     int* __restrict__ params) {
  int n = blockIdx.x * 256 + threadIdx.x;
  if (n >= NV) return;
  float h, w;
  proj_hw(verts, n, h, w);
  params[4 * n + 0] = level_off(h, w, 0.25f,    56);
  params[4 * n + 1] = level_off(h, w, 0.125f,   28);
  params[4 * n + 2] = level_off(h, w, 0.0625f,  14);
  params[4 * n + 3] = level_off(h, w, 0.03125f, 7);
}

// per-block LDS histogram of the level-3 bucket
__global__ __launch_bounds__(256) void block_hist_k(const int* __restrict__ params,
                                                    int* __restrict__ block_hist) {
  __shared__ int lh[NB];
  int t = threadIdx.x;
  if (t < NB) lh[t] = 0;
  __syncthreads();
  int n = blockIdx.x * 256 + t;
  if (n < NV) {
    int p3 = params[4 * n + 3];
    atomicAdd(&lh[(p3 < 0) ? 49 : p3], 1);
  }
  __syncthreads();
  if (t < NB) block_hist[blockIdx.x * NB + t] = lh[t];
}

// one block: blockoff[k][b] = bucket_base(b) + sum_{k'<k} block_hist[k'][b]
__global__ __launch_bounds__(64) void scan_k(const int* __restrict__ block_hist,
                                             int* __restrict__ blockoff) {
  __shared__ int tot[NB];
  int b = threadIdx.x;
  if (b < NB) {
    int acc = 0;
    for (int k = 0; k < NBLK; ++k) acc += block_hist[k * NB + b];
    tot[b] = acc;
  }
  __syncthreads();
  if (b == 0) {
    int acc = 0;
    for (int i = 0; i < NB; ++i) { int v = tot[i]; tot[i] = acc; acc += v; }
  }
  __syncthreads();
  if (b < NB) {
    int acc = tot[b];
    for (int k = 0; k < NBLK; ++k) {
      blockoff[k * NB + b] = acc;
      acc += block_hist[k * NB + b];
    }
  }
}

// re-rank within block via LDS atomics seeded from blockoff
__global__ __launch_bounds__(256) void scatter_k(const int* __restrict__ params,
                                                 const int* __restrict__ blockoff,
                                                 int* __restrict__ order) {
  __shared__ int lh[NB];
  int t = threadIdx.x;
  if (t < NB) lh[t] = blockoff[blockIdx.x * NB + t];
  __syncthreads();
  int n = blockIdx.x * 256 + t;
  if (n < NV) {
    int p3 = params[4 * n + 3];
    int pos = atomicAdd(&lh[(p3 < 0) ? 49 : p3], 1);
    order[pos] = n;  // intra-bucket order nondeterministic; output invariant
  }
}

// Wave-per-row in bucket-sorted order: 64 lanes copy row order[wid].
// Cols [0,3)=verts, [3,67)=t0, [67,195)=t1, [195,451)=t2, [451,963)=t3.
__global__ __launch_bounds__(256) void gp_sorted_k(
    const float* __restrict__ verts,
    const float* __restrict__ t0, const float* __restrict__ t1,
    const float* __restrict__ t2, const float* __restrict__ t3,
    const float* __restrict__ zeros,
    const int* __restrict__ params,
    const int* __restrict__ order,
    float* __restrict__ out) {
  int wid  = (blockIdx.x * 256 + threadIdx.x) >> 6;
  int lane = threadIdx.x & 63;
  if (wid >= NV) return;
  const int ws = __builtin_amdgcn_readfirstlane(wid);
  const int n  = __builtin_amdgcn_readfirstlane(order[ws]);  // wave-uniform

  // head elements (vector load, issued early)
  float hv = 0.0f;
  if (lane < 3) hv = verts[3 * n + lane];

  // wave-uniform param fetch (scalar path)
  int4 pv = *reinterpret_cast<const int4*>(params + 4 * n);
  int p0 = __builtin_amdgcn_readfirstlane(pv.x);
  int p1 = __builtin_amdgcn_readfirstlane(pv.y);
  int p2 = __builtin_amdgcn_readfirstlane(pv.z);
  int p3 = __builtin_amdgcn_readfirstlane(pv.w);

  // p<0 redirects into the zero block; offsets keep 16B alignment on the
  // x4 grid since (col - start_r) == 0 (mod 4).
  const float* s0 = ((p0 >= 0) ? t0 + (p0 << 6) : zeros) - 3;
  const float* s1 = ((p1 >= 0) ? t1 + (p1 << 7) : zeros) - 67;
  const float* s2 = ((p2 >= 0) ? t2 + (p2 << 8) : zeros) - 195;
  const float* s3 = ((p3 >= 0) ? t3 + (p3 << 9) : zeros) - 451;

  float* o = out + 963 * n;

  int col0 = 3 + 4 * lane;            // [3,259): t0|t1|t2
  int col1 = 259 + 4 * lane;          // [259,515): t2|t3
  int col2 = 515 + 4 * lane;          // [515,771): t3
  int col3 = 771 + 4 * lane;          // [771,963) lane<48: t3
  const float* b0 = (lane < 16) ? s0 : (lane < 48) ? s1 : s2;
  const float* b1 = (lane < 48) ? s2 : s3;
  f32x4 a = *reinterpret_cast<const f32x4*>(b0 + col0);
  f32x4 b = *reinterpret_cast<const f32x4*>(b1 + col1);
  f32x4 c = *reinterpret_cast<const f32x4*>(s3 + col2);
  f32x4 d;
  if (lane < 48) d = *reinterpret_cast<const f32x4*>(s3 + col3);

  if (lane < 3) o[lane] = hv;
  store4_u(o + col0, a);
  store4_u(o + col1, b);
  store4_u(o + col2, c);
  if (lane < 48) store4_u(o + col3, d);
}

// ---------- fallback paths ----------
template <int MODE>
__device__ __forceinline__ int get_off(const int* __restrict__ params,
                                       const float* __restrict__ verts,
                                       int n, int k, float scale, int S) {
  if (MODE < 2) return params[4 * n + k];
  float h, w;
  proj_hw(verts, n, h, w);
  return level_off(h, w, scale, S);
}

static constexpr int B_VERTS = 3 * NV;            // 150,000
static constexpr int B_F0    = B_VERTS + 64 * NV; // 3,350,000
static constexpr int B_F1    = B_F0 + 128 * NV;   // 9,750,000
static constexpr int B_F2    = B_F1 + 256 * NV;   // 22,550,000

template <int MODE>
__global__ __launch_bounds__(256) void gp_main_k(
    const float* __restrict__ verts,
    const float* __restrict__ f0, const float* __restrict__ f1,
    const float* __restrict__ f2, const float* __restrict__ f3,
    const int* __restrict__ params, float* __restrict__ out) {
  int j = blockIdx.x * 256 + threadIdx.x;
  if (j >= TOTAL) return;

  if (j < B_VERTS) {
    int n = j / 3;
    int col = j - 3 * n;
    out[n * 963 + col] = verts[j];
    return;
  }

  int n, outcol;
  float val = 0.0f;
  if (j < B_F0) {
    int t = j - B_VERTS; n = t >> 6; int c = t & 63;
    int off = get_off<MODE>(params, verts, n, 0, 0.25f, 56);
    if (off >= 0) val = f0[c * 3136 + off];
    outcol = 3 + c;
  } else if (j < B_F1) {
    int t = j - B_F0; n = t >> 7; int c = t & 127;
    int off = get_off<MODE>(params, verts, n, 1, 0.125f, 28);
    if (off >= 0) val = f1[c * 784 + off];
    outcol = 67 + c;
  } else if (j < B_F2) {
    int t = j - B_F1; n = t >> 8; int c = t & 255;
    int off = get_off<MODE>(params, verts, n, 2, 0.0625f, 14);
    if (off >= 0) val = f2[c * 196 + off];
    outcol = 195 + c;
  } else {
    int t = j - B_F2; n = t >> 9; int c = t & 511;
    int off = get_off<MODE>(params, verts, n, 3, 0.03125f, 7);
    if (off >= 0) val = f3[c * 49 + off];
    outcol = 451 + c;
  }
  out[n * 963 + outcol] = val;
}

extern "C" void kernel_launch(void* const* d_in, const int* in_sizes, int n_in,
                              void* d_out, int out_size, void* d_ws, size_t ws_size,
                              hipStream_t stream) {
  const float* f0    = (const float*)d_in[0];
  const float* f1    = (const float*)d_in[1];
  const float* f2    = (const float*)d_in[2];
  const float* f3    = (const float*)d_in[3];
  const float* verts = (const float*)d_in[4];
  float* out = (float*)d_out;

  const size_t PARAM_BYTES = (size_t)NV * 4 * sizeof(int);            // 800,000
  const size_t TAB_BYTES   = (size_t)(TSUM + ZN) * sizeof(float);     // 1,507,344
  const size_t SORT_BYTES  = PARAM_BYTES + TAB_BYTES
                           + (size_t)(2 * NBLK * NB) * sizeof(int)    // hist+off
                           + (size_t)NV * sizeof(int);                // order

  if (ws_size >= SORT_BYTES) {
    int*   params = (int*)d_ws;
    float* t0 = (float*)((char*)d_ws + PARAM_BYTES);
    float* t1 = t0 + T0;
    float* t2 = t1 + T1;
    float* t3 = t2 + T2;
    float* zeros = t3 + T3;
    int*   block_hist = (int*)(zeros + ZN);
    int*   blockoff   = block_hist + NBLK * NB;
    int*   order      = blockoff + NBLK * NB;
    transpose_k<<<(TSUM + ZN + 255) / 256, 256, 0, stream>>>(
        f0, f1, f2, f3, t0, t1, t2, t3, zeros);
    prep_params_k<<<NBLK, 256, 0, stream>>>(verts, params);
    block_hist_k<<<NBLK, 256, 0, stream>>>(params, block_hist);
    scan_k<<<1, 64, 0, stream>>>(block_hist, blockoff);
    scatter_k<<<NBLK, 256, 0, stream>>>(params, blockoff, order);
    const int rowBlocks = (NV * 64 + 255) / 256;  // 12,500
    gp_sorted_k<<<rowBlocks, 256, 0, stream>>>(verts, t0, t1, t2, t3, zeros,
                                               params, order, out);
  } else if (ws_size >= PARAM_BYTES) {
    int* params = (int*)d_ws;
    prep_params_k<<<NBLK, 256, 0, stream>>>(verts, params);
    gp_main_k<1><<<(TOTAL + 255) / 256, 256, 0, stream>>>(verts, f0, f1, f2, f3, params, out);
  } else {
    gp_main_k<2><<<(TOTAL + 255) / 256, 256, 0, stream>>>(verts, f0, f1, f2, f3, nullptr, out);
  }
}

// Round 12
// 201.741 us; speedup vs baseline: 6.2387x; 1.0886x over previous
//
#include <hip/hip_runtime.h>

// GraphProjection: out[N,963] = concat(verts[N,3], proj(f0)[N,64], proj(f1)[N,128],
//                                      proj(f2)[N,256], proj(f3)[N,512])
// Degenerate "bilinear": weights collapse to w11 = (x2-x1)*(y2-y1) in {0,1};
// every feature element is a masked gather of feat[c, floor(x), floor(y)].
//
// V12 = V5 restored (best measured: 200.7 us). Final configuration.
//
// Optimization ledger (8 falsified levers on the ~80us gp kernel):
//   - store/load vectorization x4 (V0->V5): ~null
//   - nontemporal stores (V4): -25us (write stream wants L2)
//   - fill-shaped LDS-staged line-aligned writes (V7): -26us
//   - strided 2-row MLP (V6): -30us; contiguous 2-row MLP (V9): null
//   - serial-prefix removal via scalar param fetch (V8): null
//   - read-locality bucket sort (V10 global atomics: catastrophic;
//     V11 contention-free: +17us overhead, gp unchanged -> reads already cached)
// Structural floor: 192.6 MB writes + 192.6 MB reads = 385 MB fabric traffic
// in ~80us = 4.8 TB/s combined (~75% of this harness's pure-write fill rate).
// Timed window = harness poison fill (~115us @ 80-85% peak HBM, untouchable)
// + transpose (~5us) + gp (~80us) ~= 200us.
//
//  - x4 grid anchored at col 3: region boundaries {3,67,195,451} are ==3
//    (mod 4); slice bases >=256B aligned -> all loads aligned dwordx4.
//  - stores dwordx4 at 4B alignment (plain, through L2).
//  - params computed inline per wave (wave-uniform, readfirstlane -> SGPR).
//  - cols 0..2 stored from the vert registers already loaded for projection.

static constexpr int NV      = 50000;
static constexpr int TOTAL   = 963 * NV;          // 48,150,000

// transposed feature sizes (floats): [S*S, C]
static constexpr int T0 = 56 * 56 * 64;   // 200,704
static constexpr int T1 = 28 * 28 * 128;  // 100,352
static constexpr int T2 = 14 * 14 * 256;  // 50,176
static constexpr int T3 = 7 * 7 * 512;    // 25,088
static constexpr int TSUM = T0 + T1 + T2 + T3; // 376,320
static constexpr int ZN   = 516;          // zero block (>=512 needed)

typedef float f32x4 __attribute__((ext_vector_type(4)));

__device__ __forceinline__ void store4_u(float* p, f32x4 v) {
  __builtin_memcpy(p, &v, 16);  // 4B-aligned dwordx4 store
}

__device__ __forceinline__ int level_off(float h, float w, float scale, int S) {
  float x = h * scale;  // scale = S/224 is an exact power of two
  float y = w * scale;
  int x1 = (int)floorf(x);
  int x2 = min((int)ceilf(x), S - 1);
  int y1 = (int)floorf(y);
  int y2 = min((int)ceilf(y), S - 1);
  return (x2 > x1 && y2 > y1) ? (x1 * S + y1) : -1;
}

// [C,S,S] -> [S*S, C] so per-wave channel reads are contiguous; also zero-fills
// the ZN-float zero block used for out-of-image vertices.
__global__ __launch_bounds__(256) void transpose_k(
    const float* __restrict__ f0, const float* __restrict__ f1,
    const float* __restrict__ f2, const float* __restrict__ f3,
    float* __restrict__ t0, float* __restrict__ t1,
    float* __restrict__ t2, float* __restrict__ t3,
    float* __restrict__ zeros) {
  int i = blockIdx.x * 256 + threadIdx.x;
  if (i < T0) { int off = i >> 6, c = i & 63;  t0[i] = f0[c * 3136 + off]; return; }
  i -= T0;
  if (i < T1) { int off = i >> 7, c = i & 127; t1[i] = f1[c * 784 + off];  return; }
  i -= T1;
  if (i < T2) { int off = i >> 8, c = i & 255; t2[i] = f2[c * 196 + off];  return; }
  i -= T2;
  if (i < T3) { int off = i >> 9, c = i & 511; t3[i] = f3[c * 49 + off];   return; }
  i -= T3;
  if (i < ZN) zeros[i] = 0.0f;
}

// Wave-per-vertex: 64 lanes copy one 963-dword output row with x4 accesses.
// Cols [0,3)=verts, [3,67)=t0, [67,195)=t1, [195,451)=t2, [451,963)=t3.
// s_r is positioned so s_r[col] is the right element for col in region r;
// s_r + col is 16B-aligned for col on the x4 grid (col == 3 mod 4).
__global__ __launch_bounds__(256) void gp_row_k(
    const float* __restrict__ verts,
    const float* __restrict__ t0, const float* __restrict__ t1,
    const float* __restrict__ t2, const float* __restrict__ t3,
    const float* __restrict__ zeros,
    float* __restrict__ out) {
  int wid  = (blockIdx.x * 256 + threadIdx.x) >> 6;
  int lane = threadIdx.x & 63;
  if (wid >= NV) return;
  const int n = wid;

  // wave-uniform projection (broadcast loads, identical lanes)
  float v0 = verts[3 * n + 0];
  float v1 = verts[3 * n + 1];
  float v2 = verts[3 * n + 2];
  // match numpy fp32 exactly: no FMA contraction, IEEE rn division
  float h = __fadd_rn(__fmul_rn(248.0f, __fdiv_rn(v1, v2)), 111.5f);
  float w = __fadd_rn(__fmul_rn(248.0f, __fdiv_rn(v0, -v2)), 111.5f);
  h = fminf(fmaxf(h, 0.0f), 223.0f);
  w = fminf(fmaxf(w, 0.0f), 223.0f);

  int p0 = __builtin_amdgcn_readfirstlane(level_off(h, w, 0.25f,    56));
  int p1 = __builtin_amdgcn_readfirstlane(level_off(h, w, 0.125f,   28));
  int p2 = __builtin_amdgcn_readfirstlane(level_off(h, w, 0.0625f,  14));
  int p3 = __builtin_amdgcn_readfirstlane(level_off(h, w, 0.03125f, 7));

  // p<0 redirects into the zero block; zeros - start_r keeps 16B alignment
  // since (col - start_r) == 0 (mod 4) on the x4 grid.
  const float* s0 = ((p0 >= 0) ? t0 + (p0 << 6) : zeros) - 3;
  const float* s1 = ((p1 >= 0) ? t1 + (p1 << 7) : zeros) - 67;
  const float* s2 = ((p2 >= 0) ? t2 + (p2 << 8) : zeros) - 195;
  const float* s3 = ((p3 >= 0) ? t3 + (p3 << 9) : zeros) - 451;

  float* o = out + 963 * n;

  // head: cols 0..2 from the vert registers (3 lanes)
  if (lane < 3) o[lane] = (lane == 0) ? v0 : (lane == 1) ? v1 : v2;

  // k=0: cols 3+4*lane in [3,259): t0 (lane<16), t1 (lane<48), t2 (else)
  {
    int col = 3 + 4 * lane;
    const float* b = (lane < 16) ? s0 : (lane < 48) ? s1 : s2;
    f32x4 v = *reinterpret_cast<const f32x4*>(b + col);   // aligned
    store4_u(o + col, v);
  }
  // k=1: cols 259+4*lane in [259,515): t2 (lane<48), t3 (else)
  {
    int col = 259 + 4 * lane;
    const float* b = (lane < 48) ? s2 : s3;
    f32x4 v = *reinterpret_cast<const f32x4*>(b + col);   // aligned
    store4_u(o + col, v);
  }
  // k=2: cols 515+4*lane in [515,771): all t3
  {
    int col = 515 + 4 * lane;
    f32x4 v = *reinterpret_cast<const f32x4*>(s3 + col);  // aligned
    store4_u(o + col, v);
  }
  // k=3: cols 771+4*lane in [771,963) for lane<48: all t3
  if (lane < 48) {
    int col = 771 + 4 * lane;
    f32x4 v = *reinterpret_cast<const f32x4*>(s3 + col);  // aligned
    store4_u(o + col, v);
  }
}

// ---------- fallback paths (small workspace) ----------
__device__ __forceinline__ void proj_hw(const float* __restrict__ verts, int n,
                                        float& h, float& w) {
  float v0 = verts[3 * n + 0];
  float v1 = verts[3 * n + 1];
  float v2 = verts[3 * n + 2];
  h = __fadd_rn(__fmul_rn(248.0f, __fdiv_rn(v1, v2)), 111.5f);
  w = __fadd_rn(__fmul_rn(248.0f, __fdiv_rn(v0, -v2)), 111.5f);
  h = fminf(fmaxf(h, 0.0f), 223.0f);
  w = fminf(fmaxf(w, 0.0f), 223.0f);
}

template <int MODE>
__device__ __forceinline__ int get_off(const int* __restrict__ params,
                                       const float* __restrict__ verts,
                                       int n, int k, float scale, int S) {
  if (MODE < 2) return params[4 * n + k];
  float h, w;
  proj_hw(verts, n, h, w);
  return level_off(h, w, scale, S);
}

__global__ __launch_bounds__(256) void prep_params_k(const float* __restrict__ verts,
                                                     int* __restrict__ params) {
  int n = blockIdx.x * 256 + threadIdx.x;
  if (n >= NV) return;
  float h, w;
  proj_hw(verts, n, h, w);
  params[4 * n + 0] = level_off(h, w, 0.25f,    56);
  params[4 * n + 1] = level_off(h, w, 0.125f,   28);
  params[4 * n + 2] = level_off(h, w, 0.0625f,  14);
  params[4 * n + 3] = level_off(h, w, 0.03125f, 7);
}

static constexpr int B_VERTS = 3 * NV;            // 150,000
static constexpr int B_F0    = B_VERTS + 64 * NV; // 3,350,000
static constexpr int B_F1    = B_F0 + 128 * NV;   // 9,750,000
static constexpr int B_F2    = B_F1 + 256 * NV;   // 22,550,000

template <int MODE>
__global__ __launch_bounds__(256) void gp_main_k(
    const float* __restrict__ verts,
    const float* __restrict__ f0, const float* __restrict__ f1,
    const float* __restrict__ f2, const float* __restrict__ f3,
    const int* __restrict__ params, float* __restrict__ out) {
  int j = blockIdx.x * 256 + threadIdx.x;
  if (j >= TOTAL) return;

  if (j < B_VERTS) {
    int n = j / 3;
    int col = j - 3 * n;
    out[n * 963 + col] = verts[j];
    return;
  }

  int n, outcol;
  float val = 0.0f;
  if (j < B_F0) {
    int t = j - B_VERTS; n = t >> 6; int c = t & 63;
    int off = get_off<MODE>(params, verts, n, 0, 0.25f, 56);
    if (off >= 0) val = f0[c * 3136 + off];
    outcol = 3 + c;
  } else if (j < B_F1) {
    int t = j - B_F0; n = t >> 7; int c = t & 127;
    int off = get_off<MODE>(params, verts, n, 1, 0.125f, 28);
    if (off >= 0) val = f1[c * 784 + off];
    outcol = 67 + c;
  } else if (j < B_F2) {
    int t = j - B_F1; n = t >> 8; int c = t & 255;
    int off = get_off<MODE>(params, verts, n, 2, 0.0625f, 14);
    if (off >= 0) val = f2[c * 196 + off];
    outcol = 195 + c;
  } else {
    int t = j - B_F2; n = t >> 9; int c = t & 511;
    int off = get_off<MODE>(params, verts, n, 3, 0.03125f, 7);
    if (off >= 0) val = f3[c * 49 + off];
    outcol = 451 + c;
  }
  out[n * 963 + outcol] = val;
}

extern "C" void kernel_launch(void* const* d_in, const int* in_sizes, int n_in,
                              void* d_out, int out_size, void* d_ws, size_t ws_size,
                              hipStream_t stream) {
  const float* f0    = (const float*)d_in[0];
  const float* f1    = (const float*)d_in[1];
  const float* f2    = (const float*)d_in[2];
  const float* f3    = (const float*)d_in[3];
  const float* verts = (const float*)d_in[4];
  float* out = (float*)d_out;

  const size_t PARAM_BYTES = (size_t)NV * 4 * sizeof(int);        // 800,000
  const size_t FAST_BYTES  = (size_t)(TSUM + ZN) * sizeof(float); // 1,507,344

  if (ws_size >= FAST_BYTES) {
    float* t0 = (float*)d_ws;
    float* t1 = t0 + T0;
    float* t2 = t1 + T1;
    float* t3 = t2 + T2;
    float* zeros = t3 + T3;
    transpose_k<<<(TSUM + ZN + 255) / 256, 256, 0, stream>>>(f0, f1, f2, f3,
                                                             t0, t1, t2, t3, zeros);
    const int rowBlocks = (NV * 64 + 255) / 256;  // 12,500 (one wave per vertex)
    gp_row_k<<<rowBlocks, 256, 0, stream>>>(verts, t0, t1, t2, t3, zeros, out);
  } else if (ws_size >= PARAM_BYTES) {
    int* params = (int*)d_ws;
    prep_params_k<<<(NV + 255) / 256, 256, 0, stream>>>(verts, params);
    gp_main_k<1><<<(TOTAL + 255) / 256, 256, 0, stream>>>(verts, f0, f1, f2, f3, params, out);
  } else {
    gp_main_k<2><<<(TOTAL + 255) / 256, 256, 0, stream>>>(verts, f0, f1, f2, f3, nullptr, out);
  }
}